// Round 7
// baseline (68.476 us; speedup 1.0000x reference)
//
#include <hip/hip_runtime.h>
#include <hip/hip_bf16.h>

typedef short short8 __attribute__((ext_vector_type(8)));
typedef float f32x4 __attribute__((ext_vector_type(4)));

#define CIN   128
#define COUT  128
#define HH    32
#define WW    32
#define LTOT  1024
#define KKT   9
#define KDIM  1152

// LDS: A dbuf 2 x 32KB at [0,65536); B 6 rows x 32 cols x 256B = 48KB at [65536,114688)
#define ABUF  32768
#define BOFF  65536
#define SMEM_BYTES 114688

// ---- tiny prep: wt[o*1152 + kk*128 + c] = bf16(w[(o*128+c)*9 + kk]) ----
__global__ void prep_w_kernel(const float* __restrict__ w, __hip_bfloat16* __restrict__ wt) {
  int i = blockIdx.x * 256 + threadIdx.x;     // 576 blocks -> covers 147456 exactly
  int o = i / KDIM;
  int r = i - o * KDIM;
  int kk = r >> 7, c = r & 127;
  wt[i] = __float2bfloat16(w[(o * CIN + c) * KKT + kk]);
}

__device__ __forceinline__ void gld16(const char* g, char* l) {
  __builtin_amdgcn_global_load_lds(
      (const __attribute__((address_space(1))) void*)g,
      (__attribute__((address_space(3))) void*)l, 16, 0, 0);
}

// 256 blocks x 512 threads (8 waves, 2m x 4n, wave tile 64o x 32l, mfma 16x16x32).
// B tile built IN-KERNEL from raw f32 x (fused transpose+convert), resident all taps.
// A (weights) streamed per tap from wt, double-buffered, gld16 + counted vmcnt.
// LDS chunk swizzle: slot = chunk ^ (row_or_col & 15), both sides consistent.
__global__ __launch_bounds__(512, 1)
void conv_mfma_kernel(const float* __restrict__ x,
                      const __hip_bfloat16* __restrict__ wt,
                      const float* __restrict__ mask,
                      const float* __restrict__ bias,
                      float* __restrict__ out) {
  extern __shared__ char smem[];
  const int tid = threadIdx.x;
  int bid = blockIdx.x;
  bid = (bid & 7) * 32 + (bid >> 3);     // XCD swizzle, bijective (256 % 8 == 0)
  const int b  = bid >> 3;
  const int l0 = (bid & 7) << 7;         // 128 l per block
  const int h0 = (bid & 7) << 2;         // 4 h-rows per block

  const int lane = tid & 63, wid = tid >> 6;
  const int lr = lane & 15, lg = lane >> 4;
  const int m_base = (wid >> 2) << 6;    // {0,64}
  const int n_base = (wid & 3) << 5;     // {0,32,64,96}
  const int hl = n_base >> 5;

  // ---- issue mask loads ----
  float mvA[9], mvB[9];
  {
    const float* mr = mask + l0 + n_base + lr;
#pragma unroll
    for (int kk = 0; kk < 9; ++kk) { mvA[kk] = mr[kk * LTOT]; mvB[kk] = mr[kk * LTOT + 16]; }
  }

  // ---- issue B-build loads: x[b][c][hg][w], coalesced 128B per (c,hg) ----
  const int wv = tid & 31, cg = tid >> 5;          // col (w), 16-B chunk (8 c's)
  char* bdst = smem + BOFF + wv * 256 + (((cg ^ (wv & 15))) << 4);
  const float* xb = x + (size_t)b * CIN * LTOT;
  float fr[6][8];
#pragma unroll
  for (int r = 0; r < 6; ++r) {
    const int hg = h0 - 1 + r;
    if ((unsigned)hg < (unsigned)HH) {             // block-uniform branch
      const float* s = xb + (size_t)cg * 8 * LTOT + hg * WW + wv;
#pragma unroll
      for (int j = 0; j < 8; ++j) fr[r][j] = s[(size_t)j * LTOT];
    }
  }
  asm volatile("s_waitcnt vmcnt(0)" ::: "memory");
#pragma unroll
  for (int kk = 0; kk < 9; ++kk)
    asm volatile("" : "+v"(mvA[kk]), "+v"(mvB[kk]));

  // ---- convert + write B tile (zero OOB rows) ----
#pragma unroll
  for (int r = 0; r < 6; ++r) {
    const int hg = h0 - 1 + r;
    short8 v = (short8){0, 0, 0, 0, 0, 0, 0, 0};
    if ((unsigned)hg < (unsigned)HH) {
#pragma unroll
      for (int j = 0; j < 8; ++j)
        v[j] = (short)__builtin_bit_cast(unsigned short, __float2bfloat16(fr[r][j]));
    }
    *(short8*)(bdst + r * 8192) = v;
  }

  // ---- A staging: 4 gld16/thread per tap tile (32 KB) ----
  const int t4 = tid >> 4, ch = tid & 15;
  const int cx = ((ch ^ (t4 & 15)) << 4);
  int asrc[4];
#pragma unroll
  for (int r = 0; r < 4; ++r) asrc[r] = (r * 32 + t4) * 2304 + cx;
  const char* wtc = (const char*)wt;
  auto stageA = [&](int kk) {
    const char* s = wtc + kk * 256;
    char* d = smem + (kk & 1) * ABUF + tid * 16;
#pragma unroll
    for (int r = 0; r < 4; ++r) gld16(s + asrc[r], d + r * 8192);
  };
  stageA(0);
  stageA(1);
  asm volatile("s_waitcnt lgkmcnt(0)" ::: "memory");   // B writes done (mine)

  f32x4 acc[4][2], par[4][2];
#pragma unroll
  for (int mi = 0; mi < 4; ++mi)
#pragma unroll
    for (int nj = 0; nj < 2; ++nj) {
      acc[mi][nj] = (f32x4){0.f, 0.f, 0.f, 0.f};
      par[mi][nj] = (f32x4){0.f, 0.f, 0.f, 0.f};
    }

#pragma unroll
  for (int kk = 0; kk < 9; ++kk) {
    if (kk < 8) asm volatile("s_waitcnt vmcnt(4)" ::: "memory");  // A(kk) done, A(kk+1) in flight
    else        asm volatile("s_waitcnt vmcnt(0)" ::: "memory");
    __builtin_amdgcn_s_barrier();

    const char* A = smem + (kk & 1) * ABUF;
    const int di = (kk * 11) >> 5;               // kk/3
    const int dj = kk - 3 * di;
    // nj=0: col = lr+dj-1 (OOB iff lr==0,dj==0); nj=1: col = 16+lr+dj-1 (OOB iff lr==15,dj==2)
    const int col0 = lr + dj - 1;
    const int col1 = 16 + lr + dj - 1;
    const bool v0 = (unsigned)col0 < (unsigned)WW;
    const bool v1 = (unsigned)col1 < (unsigned)WW;
    const int cc0 = v0 ? col0 : 0;
    const int cc1 = v1 ? col1 : 0;
    const char* B0 = smem + BOFF + (hl + di) * 8192 + cc0 * 256;
    const char* B1 = smem + BOFF + (hl + di) * 8192 + cc1 * 256;
    const int x0 = cc0 & 15, x1 = cc1 & 15;
    const char* A0 = A + (m_base      + lr) * 256;
    const char* A1 = A + (m_base + 16 + lr) * 256;
    const char* A2 = A + (m_base + 32 + lr) * 256;
    const char* A3 = A + (m_base + 48 + lr) * 256;

    __builtin_amdgcn_s_setprio(1);
#pragma unroll
    for (int ks = 0; ks < 4; ++ks) {
      const int q = ks * 4 + lg;
      short8 af0 = *(const short8*)(A0 + ((q ^ lr) << 4));
      short8 af1 = *(const short8*)(A1 + ((q ^ lr) << 4));
      short8 af2 = *(const short8*)(A2 + ((q ^ lr) << 4));
      short8 af3 = *(const short8*)(A3 + ((q ^ lr) << 4));
      short8 bf0 = *(const short8*)(B0 + ((q ^ x0) << 4));
      short8 bf1 = *(const short8*)(B1 + ((q ^ x1) << 4));
      par[0][0] = __builtin_amdgcn_mfma_f32_16x16x32_bf16(af0, bf0, par[0][0], 0, 0, 0);
      par[1][0] = __builtin_amdgcn_mfma_f32_16x16x32_bf16(af1, bf0, par[1][0], 0, 0, 0);
      par[2][0] = __builtin_amdgcn_mfma_f32_16x16x32_bf16(af2, bf0, par[2][0], 0, 0, 0);
      par[3][0] = __builtin_amdgcn_mfma_f32_16x16x32_bf16(af3, bf0, par[3][0], 0, 0, 0);
      par[0][1] = __builtin_amdgcn_mfma_f32_16x16x32_bf16(af0, bf1, par[0][1], 0, 0, 0);
      par[1][1] = __builtin_amdgcn_mfma_f32_16x16x32_bf16(af1, bf1, par[1][1], 0, 0, 0);
      par[2][1] = __builtin_amdgcn_mfma_f32_16x16x32_bf16(af2, bf1, par[2][1], 0, 0, 0);
      par[3][1] = __builtin_amdgcn_mfma_f32_16x16x32_bf16(af3, bf1, par[3][1], 0, 0, 0);
    }
    __builtin_amdgcn_s_setprio(0);

    // mask fold; OOB column taps contribute 0 (garbage * 0)
    const float m0 = v0 ? mvA[kk] : 0.f;
    const float m1 = v1 ? mvB[kk] : 0.f;
#pragma unroll
    for (int mi = 0; mi < 4; ++mi)
#pragma unroll
      for (int rr = 0; rr < 4; ++rr) {
        acc[mi][0][rr] += m0 * par[mi][0][rr];  par[mi][0][rr] = 0.f;
        acc[mi][1][rr] += m1 * par[mi][1][rr];  par[mi][1][rr] = 0.f;
      }

    asm volatile("s_waitcnt lgkmcnt(0)" ::: "memory");  // my buf reads retired
    __builtin_amdgcn_s_barrier();
    if (kk <= 6) stageA(kk + 2);                        // refill buffer just read
  }

  // ---- epilogue (r4-verified): col(l)=lane&15, row(o)=(lane>>4)*4+rr ----
  float* outb = out + (size_t)b * COUT * LTOT + l0;
#pragma unroll
  for (int mi = 0; mi < 4; ++mi) {
#pragma unroll
    for (int rr = 0; rr < 4; ++rr) {
      int o = m_base + mi * 16 + lg * 4 + rr;
      float bv = bias[o];
      outb[(size_t)o * LTOT + n_base      + lr] = acc[mi][0][rr] + bv;
      outb[(size_t)o * LTOT + n_base + 16 + lr] = acc[mi][1][rr] + bv;
    }
  }
}

extern "C" void kernel_launch(void* const* d_in, const int* in_sizes, int n_in,
                              void* d_out, int out_size, void* d_ws, size_t ws_size,
                              hipStream_t stream) {
  const float* x    = (const float*)d_in[0];
  const float* mask = (const float*)d_in[1];
  const float* w    = (const float*)d_in[2];
  const float* bias = (const float*)d_in[3];
  float* out = (float*)d_out;
  __hip_bfloat16* wt = (__hip_bfloat16*)d_ws;

  (void)hipFuncSetAttribute(reinterpret_cast<const void*>(conv_mfma_kernel),
                            hipFuncAttributeMaxDynamicSharedMemorySize, SMEM_BYTES);

  prep_w_kernel<<<576, 256, 0, stream>>>(w, wt);
  // A/B measurement round: launch conv TWICE (idempotent — same inputs, same output).
  // Dispatch #2 runs warm and gives the first direct hot-conv reading in rocprof;
  // total' - 39.0us gives hot-conv time under graph replay.
  conv_mfma_kernel<<<256, 512, SMEM_BYTES, stream>>>(x, wt, mask, bias, out);
  conv_mfma_kernel<<<256, 512, SMEM_BYTES, stream>>>(x, wt, mask, bias, out);
}

// Round 8
// 38.476 us; speedup vs baseline: 1.7797x; 1.7797x over previous
//
#include <hip/hip_runtime.h>
#include <hip/hip_bf16.h>

typedef short short8 __attribute__((ext_vector_type(8)));
typedef float f32x4 __attribute__((ext_vector_type(4)));

#define CIN   128
#define COUT  128
#define HH    32
#define WW    32
#define LTOT  1024
#define KKT   9
#define KDIM  1152

// LDS per block: A dbuf 2 x 16KB at [0,32768); B 6 rows x 32 cols x 256B = 48KB
// at [32768, 81920). Total 80KB -> exactly 2 blocks/CU.
#define ABUF  16384
#define BOFF  32768
#define SMEM_BYTES 81920

// ---- tiny prep: wt[o*1152 + kk*128 + c] = bf16(w[(o*128+c)*9 + kk]) ----
__global__ void prep_w_kernel(const float* __restrict__ w, __hip_bfloat16* __restrict__ wt) {
  int i = blockIdx.x * 256 + threadIdx.x;     // 576 blocks -> covers 147456 exactly
  int o = i / KDIM;
  int r = i - o * KDIM;
  int kk = r >> 7, c = r & 127;
  wt[i] = __float2bfloat16(w[(o * CIN + c) * KKT + kk]);
}

__device__ __forceinline__ void gld16(const char* g, char* l) {
  __builtin_amdgcn_global_load_lds(
      (const __attribute__((address_space(1))) void*)g,
      (__attribute__((address_space(3))) void*)l, 16, 0, 0);
}

// 512 blocks x 256 threads (4 waves, 1m x 4n, wave tile 64o x 32l, mfma 16x16x32).
// Block tile 64(o) x 128(l); o-half in bid bit0 (paired blocks share B locality).
// B tile built in-kernel from raw f32 x (fused transpose+convert), resident all taps.
// A (weights) streamed per tap from wt, double-buffered, gld16 + counted vmcnt.
// LDS chunk swizzle: slot = chunk ^ (row_or_col & 15), both sides consistent.
__global__ __launch_bounds__(256, 2)
void conv_mfma_kernel(const float* __restrict__ x,
                      const __hip_bfloat16* __restrict__ wt,
                      const float* __restrict__ mask,
                      const float* __restrict__ bias,
                      float* __restrict__ out) {
  extern __shared__ char smem[];
  const int tid = threadIdx.x;
  int bid = blockIdx.x;
  bid = (bid & 7) * 64 + (bid >> 3);     // XCD swizzle, bijective (512 % 8 == 0)
  const int b  = bid >> 4;
  const int o0 = (bid & 1) << 6;         // 64 o per block
  const int l0 = ((bid >> 1) & 7) << 7;  // 128 l per block
  const int h0 = ((bid >> 1) & 7) << 2;  // 4 h-rows per block

  const int lane = tid & 63, wid = tid >> 6;
  const int lr = lane & 15, lg = lane >> 4;
  const int n_base = wid << 5;           // {0,32,64,96}
  const int hl = wid;                    // n_base>>5

  // ---- issue mask loads ----
  float mvA[9], mvB[9];
  {
    const float* mr = mask + l0 + n_base + lr;
#pragma unroll
    for (int kk = 0; kk < 9; ++kk) { mvA[kk] = mr[kk * LTOT]; mvB[kk] = mr[kk * LTOT + 16]; }
  }

  // ---- B-build: x[b][c][hg][w] -> bf16 tile, two passes (reg pressure) ----
  const int wv = tid & 31, cg = tid >> 5;          // col (w), chunk-group 0..7
  const float* xb = x + (size_t)b * CIN * LTOT;
  for (int p = 0; p < 2; ++p) {
    const int q = cg + p * 8;                      // 16-B chunk 0..15 (8 c's)
    char* bdst = smem + BOFF + wv * 256 + ((q ^ (wv & 15)) << 4);
    float fr[6][8];
#pragma unroll
    for (int r = 0; r < 6; ++r) {
      const int hg = h0 - 1 + r;
      if ((unsigned)hg < (unsigned)HH) {           // block-uniform branch
        const float* s = xb + (size_t)q * 8 * LTOT + hg * WW + wv;
#pragma unroll
        for (int j = 0; j < 8; ++j) fr[r][j] = s[(size_t)j * LTOT];
      }
    }
    asm volatile("s_waitcnt vmcnt(0)" ::: "memory");
#pragma unroll
    for (int r = 0; r < 6; ++r) {
      const int hg = h0 - 1 + r;
      short8 v = (short8){0, 0, 0, 0, 0, 0, 0, 0};
      if ((unsigned)hg < (unsigned)HH) {
#pragma unroll
        for (int j = 0; j < 8; ++j)
          v[j] = (short)__builtin_bit_cast(unsigned short, __float2bfloat16(fr[r][j]));
      }
      *(short8*)(bdst + r * 8192) = v;
    }
  }
#pragma unroll
  for (int kk = 0; kk < 9; ++kk)
    asm volatile("" : "+v"(mvA[kk]), "+v"(mvB[kk]));   // masks resident past the drains

  // ---- A staging: 4 gld16/thread per tap tile (16 KB: 64 rows x 256 B) ----
  const int t4 = tid >> 4, ch = tid & 15;
  const int cx = ((ch ^ (t4 & 15)) << 4);
  int asrc[4];
#pragma unroll
  for (int r = 0; r < 4; ++r) asrc[r] = (r * 16 + t4) * 2304 + cx;
  const char* wtc = (const char*)wt + (size_t)o0 * 2304;
  auto stageA = [&](int kk) {
    const char* s = wtc + kk * 256;
    char* d = smem + (kk & 1) * ABUF + tid * 16;
#pragma unroll
    for (int r = 0; r < 4; ++r) gld16(s + asrc[r], d + r * 4096);
  };
  stageA(0);
  stageA(1);
  asm volatile("s_waitcnt lgkmcnt(0)" ::: "memory");   // my B writes done

  f32x4 acc[4][2], par[4][2];
#pragma unroll
  for (int mi = 0; mi < 4; ++mi)
#pragma unroll
    for (int nj = 0; nj < 2; ++nj) {
      acc[mi][nj] = (f32x4){0.f, 0.f, 0.f, 0.f};
      par[mi][nj] = (f32x4){0.f, 0.f, 0.f, 0.f};
    }

#pragma unroll
  for (int kk = 0; kk < 9; ++kk) {
    if (kk < 8) asm volatile("s_waitcnt vmcnt(4)" ::: "memory");  // A(kk) done, A(kk+1) in flight
    else        asm volatile("s_waitcnt vmcnt(0)" ::: "memory");
    __builtin_amdgcn_s_barrier();

    const char* A = smem + (kk & 1) * ABUF;
    const int di = (kk * 11) >> 5;               // kk/3
    const int dj = kk - 3 * di;
    const int col0 = lr + dj - 1;                // OOB iff lr==0 && dj==0
    const int col1 = 16 + lr + dj - 1;           // OOB iff lr==15 && dj==2
    const bool v0 = (unsigned)col0 < (unsigned)WW;
    const bool v1 = (unsigned)col1 < (unsigned)WW;
    const int cc0 = v0 ? col0 : 0;
    const int cc1 = v1 ? col1 : 0;
    const char* B0 = smem + BOFF + (hl + di) * 8192 + cc0 * 256;
    const char* B1 = smem + BOFF + (hl + di) * 8192 + cc1 * 256;
    const int x0 = cc0 & 15, x1 = cc1 & 15;
    const char* A0 = A + (lr)      * 256;
    const char* A1 = A + (16 + lr) * 256;
    const char* A2 = A + (32 + lr) * 256;
    const char* A3 = A + (48 + lr) * 256;

    __builtin_amdgcn_s_setprio(1);
#pragma unroll
    for (int ks = 0; ks < 4; ++ks) {
      const int q = ks * 4 + lg;
      short8 af0 = *(const short8*)(A0 + ((q ^ lr) << 4));
      short8 af1 = *(const short8*)(A1 + ((q ^ lr) << 4));
      short8 af2 = *(const short8*)(A2 + ((q ^ lr) << 4));
      short8 af3 = *(const short8*)(A3 + ((q ^ lr) << 4));
      short8 bf0 = *(const short8*)(B0 + ((q ^ x0) << 4));
      short8 bf1 = *(const short8*)(B1 + ((q ^ x1) << 4));
      par[0][0] = __builtin_amdgcn_mfma_f32_16x16x32_bf16(af0, bf0, par[0][0], 0, 0, 0);
      par[1][0] = __builtin_amdgcn_mfma_f32_16x16x32_bf16(af1, bf0, par[1][0], 0, 0, 0);
      par[2][0] = __builtin_amdgcn_mfma_f32_16x16x32_bf16(af2, bf0, par[2][0], 0, 0, 0);
      par[3][0] = __builtin_amdgcn_mfma_f32_16x16x32_bf16(af3, bf0, par[3][0], 0, 0, 0);
      par[0][1] = __builtin_amdgcn_mfma_f32_16x16x32_bf16(af0, bf1, par[0][1], 0, 0, 0);
      par[1][1] = __builtin_amdgcn_mfma_f32_16x16x32_bf16(af1, bf1, par[1][1], 0, 0, 0);
      par[2][1] = __builtin_amdgcn_mfma_f32_16x16x32_bf16(af2, bf1, par[2][1], 0, 0, 0);
      par[3][1] = __builtin_amdgcn_mfma_f32_16x16x32_bf16(af3, bf1, par[3][1], 0, 0, 0);
    }
    __builtin_amdgcn_s_setprio(0);

    // mask fold; OOB column taps contribute 0 (garbage * 0)
    const float m0 = v0 ? mvA[kk] : 0.f;
    const float m1 = v1 ? mvB[kk] : 0.f;
#pragma unroll
    for (int mi = 0; mi < 4; ++mi)
#pragma unroll
      for (int rr = 0; rr < 4; ++rr) {
        acc[mi][0][rr] += m0 * par[mi][0][rr];  par[mi][0][rr] = 0.f;
        acc[mi][1][rr] += m1 * par[mi][1][rr];  par[mi][1][rr] = 0.f;
      }

    asm volatile("s_waitcnt lgkmcnt(0)" ::: "memory");  // my buf reads retired
    __builtin_amdgcn_s_barrier();
    if (kk <= 6) stageA(kk + 2);                        // refill buffer just read
  }

  // ---- epilogue (verified): col(l)=lane&15, row(o)=(lane>>4)*4+rr ----
  float* outb = out + (size_t)b * COUT * LTOT + (size_t)o0 * LTOT + l0;
#pragma unroll
  for (int mi = 0; mi < 4; ++mi) {
#pragma unroll
    for (int rr = 0; rr < 4; ++rr) {
      int o = mi * 16 + lg * 4 + rr;
      float bv = bias[o0 + o];
      outb[(size_t)o * LTOT + n_base      + lr] = acc[mi][0][rr] + bv;
      outb[(size_t)o * LTOT + n_base + 16 + lr] = acc[mi][1][rr] + bv;
    }
  }
}

extern "C" void kernel_launch(void* const* d_in, const int* in_sizes, int n_in,
                              void* d_out, int out_size, void* d_ws, size_t ws_size,
                              hipStream_t stream) {
  const float* x    = (const float*)d_in[0];
  const float* mask = (const float*)d_in[1];
  const float* w    = (const float*)d_in[2];
  const float* bias = (const float*)d_in[3];
  float* out = (float*)d_out;
  __hip_bfloat16* wt = (__hip_bfloat16*)d_ws;

  (void)hipFuncSetAttribute(reinterpret_cast<const void*>(conv_mfma_kernel),
                            hipFuncAttributeMaxDynamicSharedMemorySize, SMEM_BYTES);

  prep_w_kernel<<<576, 256, 0, stream>>>(w, wt);
  conv_mfma_kernel<<<512, 256, SMEM_BYTES, stream>>>(x, wt, mask, bias, out);
}